// Round 2
// baseline (1435.057 us; speedup 1.0000x reference)
//
#include <hip/hip_runtime.h>

// VectorQuantizer forward, MI355X. Split-bf16 MFMA GEMM (hi/lo, 3 products,
// K extended 256->768), fused argmin + d^2 sums + tile-local candidate capture
// in a SINGLE GEMM pass. T=4096 tokens, NE=16384 codes.

#define T_TOK 4096
#define NE    16384
#define KD    256
#define K3    768          // 3x split-extended K
#define CAP   1024         // candidate slots per token
#define DCUT  0.2f         // capture window above tile-local min (e^-20 floor)

typedef __attribute__((ext_vector_type(8))) short bf16x8;
typedef __attribute__((ext_vector_type(4))) float f32x4;
typedef unsigned long long u64;

__device__ __forceinline__ short f2bf(float f) {
    unsigned u = __float_as_uint(f);
    u = (u + 0x7FFFu + ((u >> 16) & 1u)) >> 16;   // round-to-nearest-even
    return (short)u;
}
__device__ __forceinline__ float bf2f(short s) {
    return __uint_as_float(((unsigned)(unsigned short)s) << 16);
}

__device__ __forceinline__ void async_load16(const void* g, void* l) {
    __builtin_amdgcn_global_load_lds(
        (const __attribute__((address_space(1))) void*)g,
        (__attribute__((address_space(3))) void*)l, 16, 0, 0);
}

// ---------------- init ----------------
__global__ void vq_init_kernel(u64* __restrict__ packed, float* __restrict__ avg_num,
                               int* __restrict__ ncand, float* __restrict__ scal) {
    int i = blockIdx.x * 256 + threadIdx.x;
    if (i < T_TOK) packed[i] = ~0ull;
    if (i < NE)    avg_num[i] = 0.f;
    if (i < T_TOK) ncand[i] = 0;
    if (i < 8)     scal[i] = 0.f;
}

// ---------------- normalize codebooks -> enorm fp32, e2, Es (split bf16, -2x) ----------------
__global__ void norm_codes_kernel(const float* __restrict__ wk, const float* __restrict__ wg,
                                  float* __restrict__ enorm, float* __restrict__ e2k,
                                  float* __restrict__ e2g, short* __restrict__ Es) {
    int n = blockIdx.x, c = threadIdx.x;
    int lane = c & 63, w = c >> 6;
    float x = (c < 64) ? wk[n * 64 + c] : wg[n * 192 + (c - 64)];
    float s = x * x;
#pragma unroll
    for (int m = 1; m < 64; m <<= 1) s += __shfl_xor(s, m, 64);
    __shared__ float ws4[4];
    if (lane == 0) ws4[w] = s;
    __syncthreads();
    float sk = ws4[0], sg = ws4[1] + ws4[2] + ws4[3];
    float nk = fmaxf(sqrtf(sk), 1e-12f), ng = fmaxf(sqrtf(sg), 1e-12f);
    float y = x / ((c < 64) ? nk : ng);
    enorm[(size_t)n * KD + c] = y;
    if (c == 0) { e2k[n] = sk / (nk * nk); e2g[n] = sg / (ng * ng); }
    short h = f2bf(y);          float hf = bf2f(h);
    short l = f2bf(y - hf);     float lf = bf2f(l);
    short sh = f2bf(-2.f * hf), sl = f2bf(-2.f * lf);   // exact scaling
    short* Er = Es + (size_t)n * K3;
    if (c < 64) { Er[c] = sh; Er[64 + c] = sl; Er[128 + c] = sh; }
    else { int cc = c - 64; Er[192 + cc] = sh; Er[384 + cc] = sl; Er[576 + cc] = sh; }
}

// ---------------- normalize z (NCHW->token) -> znorm fp32, z2, Zs (split bf16) ----------------
__global__ void norm_z_kernel(const float* __restrict__ z, float* __restrict__ znorm,
                              float* __restrict__ z2k, float* __restrict__ z2g,
                              short* __restrict__ Zs) {
    int t = blockIdx.x, c = threadIdx.x;
    int lane = c & 63, w = c >> 6;
    int b = t >> 10, hw = t & 1023;
    float x = z[((size_t)b * 256 + c) * 1024 + hw];
    float s = x * x;
#pragma unroll
    for (int m = 1; m < 64; m <<= 1) s += __shfl_xor(s, m, 64);
    __shared__ float ws4[4];
    if (lane == 0) ws4[w] = s;
    __syncthreads();
    float sk = ws4[0], sg = ws4[1] + ws4[2] + ws4[3];
    float nk = fmaxf(sqrtf(sk), 1e-12f), ng = fmaxf(sqrtf(sg), 1e-12f);
    float y = x / ((c < 64) ? nk : ng);
    znorm[(size_t)t * KD + c] = y;
    if (c == 0) { z2k[t] = sk / (nk * nk); z2g[t] = sg / (ng * ng); }
    short h = f2bf(y);      float hf = bf2f(h);
    short l = f2bf(y - hf);
    short* Zr = Zs + (size_t)t * K3;
    if (c < 64) { Zr[c] = h; Zr[64 + c] = h; Zr[128 + c] = l; }
    else { int cc = c - 64; Zr[192 + cc] = h; Zr[384 + cc] = h; Zr[576 + cc] = l; }
}

// ---------------- fused MFMA GEMM: argmin + d^2 sums + candidate capture ----------------
__global__ __launch_bounds__(256, 2)
void gemm_fused_kernel(const short* __restrict__ Zs, const short* __restrict__ Es,
                       const float* __restrict__ z2k, const float* __restrict__ z2g,
                       const float* __restrict__ e2k, const float* __restrict__ e2g,
                       u64* __restrict__ packed, float* __restrict__ scal,
                       float* __restrict__ candD, int* __restrict__ candN,
                       int* __restrict__ ncand) {
    __shared__ __align__(16) short As[128 * 64];   // [token_row][k] 64 bf16/row
    __shared__ __align__(16) short Bs[128 * 64];   // [code_row][k]
    const int tid = threadIdx.x;
    const int lane = tid & 63, wid = tid >> 6;
    const int wm = wid >> 1, wn = wid & 1;         // wave tile: 64(tok) x 64(code)
    const int n0 = blockIdx.x * 128, t0 = blockIdx.y * 128;

    f32x4 acck[4][4], accg[4][4];
#pragma unroll
    for (int bi = 0; bi < 4; ++bi)
#pragma unroll
        for (int bj = 0; bj < 4; ++bj) {
            f32x4 zz = {0.f, 0.f, 0.f, 0.f};
            acck[bi][bj] = zz; accg[bi][bj] = zz;
        }

    auto stage = [&](int k0) {
        const int rb0 = wid * 32;
#pragma unroll
        for (int c2 = 0; c2 < 4; ++c2) {
            int rb = rb0 + c2 * 8;
            int row = rb + (lane >> 3);
            int q = (lane & 7) ^ (lane >> 3);   // XOR-quad swizzle (rb%8==0)
            async_load16(Zs + (size_t)(t0 + row) * K3 + k0 + q * 8, &As[rb * 64]);
            async_load16(Es + (size_t)(n0 + row) * K3 + k0 + q * 8, &Bs[rb * 64]);
        }
    };
    auto compute_half = [&](f32x4 (&acc)[4][4], int s) {
        bf16x8 af[4], bfv[4];
#pragma unroll
        for (int bi = 0; bi < 4; ++bi) {
            int arow = wm * 64 + bi * 16 + (lane & 15);
            int q = ((s << 2) | (lane >> 4)) ^ (arow & 7);
            af[bi] = *reinterpret_cast<const bf16x8*>(&As[arow * 64 + q * 8]);
        }
#pragma unroll
        for (int bj = 0; bj < 4; ++bj) {
            int brow = wn * 64 + bj * 16 + (lane & 15);
            int q = ((s << 2) | (lane >> 4)) ^ (brow & 7);
            bfv[bj] = *reinterpret_cast<const bf16x8*>(&Bs[brow * 64 + q * 8]);
        }
#pragma unroll
        for (int bi = 0; bi < 4; ++bi)
#pragma unroll
            for (int bj = 0; bj < 4; ++bj)
                acc[bi][bj] = __builtin_amdgcn_mfma_f32_16x16x32_bf16(
                    af[bi], bfv[bj], acc[bi][bj], 0, 0, 0);
    };

    int k0 = 0;
    for (int r = 0; r < 3; ++r) {              // k-part segment -> acc = -2*dot_k
        stage(k0); __syncthreads();
        compute_half(acck, 0); compute_half(acck, 1);
        __syncthreads(); k0 += 64;
    }
    for (int r = 0; r < 9; ++r) {              // g-part segment -> acc = -2*dot_g
        stage(k0); __syncthreads();
        compute_half(accg, 0); compute_half(accg, 1);
        __syncthreads(); k0 += 64;
    }

    // ---- epilogue: d = (z2k+e2k-2dotk) + (z2g+e2g-2dotg) ----
    float e2kv[4], e2gv[4];
#pragma unroll
    for (int bj = 0; bj < 4; ++bj) {
        int n = n0 + wn * 64 + bj * 16 + (lane & 15);
        e2kv[bj] = e2k[n]; e2gv[bj] = e2g[n];
    }
    float sdk2 = 0.f, sdg2 = 0.f;
    u64* tokmin = (u64*)Bs;                    // 128 tokens x 2 wn halves

    // pass 1: per-token wave-local packed min (d,n), d^2 sums
#pragma unroll
    for (int bi = 0; bi < 4; ++bi) {
        u64 pmin[4] = {~0ull, ~0ull, ~0ull, ~0ull};
#pragma unroll
        for (int reg = 0; reg < 4; ++reg) {
            int t = t0 + wm * 64 + bi * 16 + (lane >> 4) * 4 + reg;
            float zk2 = z2k[t], zg2 = z2g[t];
#pragma unroll
            for (int bj = 0; bj < 4; ++bj) {
                float dk = zk2 + e2kv[bj] + acck[bi][bj][reg];
                float dg = zg2 + e2gv[bj] + accg[bi][bj][reg];
                float d = dk + dg;
                sdk2 = fmaf(dk, dk, sdk2);
                sdg2 = fmaf(dg, dg, sdg2);
                int n = n0 + wn * 64 + bj * 16 + (lane & 15);
                u64 pv = (((u64)__float_as_uint(d)) << 32) | (unsigned)n;
                if (pv < pmin[reg]) pmin[reg] = pv;
            }
        }
#pragma unroll
        for (int m = 1; m < 16; m <<= 1)
#pragma unroll
            for (int reg = 0; reg < 4; ++reg) {
                u64 o = __shfl_xor(pmin[reg], m, 64);
                if (o < pmin[reg]) pmin[reg] = o;
            }
        if ((lane & 15) == 0) {
#pragma unroll
            for (int reg = 0; reg < 4; ++reg) {
                int tl = wm * 64 + bi * 16 + (lane >> 4) * 4 + reg;
                tokmin[tl * 2 + wn] = pmin[reg];
            }
        }
    }
    __syncthreads();

    // pass 2: block-level (128-code) min -> global atomicMin + candidate capture
#pragma unroll
    for (int bi = 0; bi < 4; ++bi) {
#pragma unroll
        for (int reg = 0; reg < 4; ++reg) {
            int tl = wm * 64 + bi * 16 + (lane >> 4) * 4 + reg;
            int t = t0 + tl;
            u64 bm = tokmin[tl * 2], b1 = tokmin[tl * 2 + 1];
            if (b1 < bm) bm = b1;
            if (wn == 0 && (lane & 15) == 0) atomicMin(&packed[t], bm);
            float thr = __uint_as_float((unsigned)(bm >> 32)) + DCUT;
            float zk2 = z2k[t], zg2 = z2g[t];
#pragma unroll
            for (int bj = 0; bj < 4; ++bj) {
                float dk = zk2 + e2kv[bj] + acck[bi][bj][reg];
                float dg = zg2 + e2gv[bj] + accg[bi][bj][reg];
                float d = dk + dg;                    // identical expr to pass 1
                if (d <= thr) {
                    int pos = atomicAdd(&ncand[t], 1);
                    if (pos < CAP) {
                        candD[(size_t)t * CAP + pos] = d;
                        candN[(size_t)t * CAP + pos] = n0 + wn * 64 + bj * 16 + (lane & 15);
                    }
                }
            }
        }
    }

    // block-reduce d^2 partial sums
    float* red = (float*)As;
    red[tid] = sdk2; __syncthreads();
    for (int s = 128; s > 0; s >>= 1) { if (tid < s) red[tid] += red[tid + s]; __syncthreads(); }
    if (tid == 0) atomicAdd(&scal[0], red[0]);
    __syncthreads();
    red[tid] = sdg2; __syncthreads();
    for (int s = 128; s > 0; s >>= 1) { if (tid < s) red[tid] += red[tid + s]; __syncthreads(); }
    if (tid == 0) atomicAdd(&scal[1], red[0]);
}

// ---------------- unpack argmin ----------------
__global__ void argmin_kernel(const u64* __restrict__ packed, float* __restrict__ m_arr,
                              int* __restrict__ idx_arr, float* __restrict__ out) {
    int t = blockIdx.x * 256 + threadIdx.x;
    if (t >= T_TOK) return;
    u64 pv = packed[t];
    int idx = (int)(pv & 0xFFFFFFFFull);
    float dmin = __uint_as_float((unsigned)(pv >> 32));
    m_arr[t] = -100.f * dmin;
    idx_arr[t] = idx;
    out[1048581 + t] = (float)idx;
}

// ---------------- z_q gather + vq loss ----------------
__global__ void zq_kernel(const float* __restrict__ enorm, const float* __restrict__ znorm,
                          const int* __restrict__ idx_arr,
                          float* __restrict__ out, float* __restrict__ scal) {
    int t = blockIdx.x, c = threadIdx.x;
    int b = t >> 10, hw = t & 1023;
    float q = enorm[(size_t)idx_arr[t] * KD + c];
    float zc = znorm[(size_t)t * KD + c];
    out[((size_t)b * 256 + c) * 1024 + hw] = q;
    float df = q - zc;
    __shared__ float red[256];
    red[c] = df * df;
    __syncthreads();
    for (int s = 128; s > 0; s >>= 1) { if (c < s) red[c] += red[c + s]; __syncthreads(); }
    if (c == 0) atomicAdd(&scal[2], red[0]);
}

// ---------------- per-token softmax/entropy from candidates ----------------
__global__ void token_entropy_kernel(const float* __restrict__ candD, const int* __restrict__ candN,
                                     const int* __restrict__ ncand, const float* __restrict__ m_arr,
                                     float* __restrict__ avg_num, float* __restrict__ scal) {
    int t = blockIdx.x, lane = threadIdx.x;  // 64
    int nc = min(ncand[t], CAP);
    float m = m_arr[t];
    float Z = 0.f, W = 0.f;
    for (int i = lane; i < nc; i += 64) {
        float a = -100.f * candD[(size_t)t * CAP + i];
        float e = expf(a - m);
        Z += e; W = fmaf(e, a, W);
    }
#pragma unroll
    for (int mm = 1; mm < 64; mm <<= 1) {
        Z += __shfl_xor(Z, mm, 64);
        W += __shfl_xor(W, mm, 64);
    }
    if (lane == 0) atomicAdd(&scal[3], m + logf(Z) - W / Z);
    for (int i = lane; i < nc; i += 64) {
        float a = -100.f * candD[(size_t)t * CAP + i];
        float e = expf(a - m);
        atomicAdd(&avg_num[candN[(size_t)t * CAP + i]], e / Z);
    }
}

// ---------------- final scalars ----------------
__global__ void finalize_kernel(const float* __restrict__ avg_num, const float* __restrict__ scal,
                                float* __restrict__ out) {
    __shared__ float red[256];
    int tid = threadIdx.x;
    float s = 0.f;
    for (int n = tid; n < NE; n += 256) {
        float avg = avg_num[n] * (1.f / 4096.f);
        s += avg * logf(avg + 1e-5f);
    }
    red[tid] = s;
    __syncthreads();
    for (int st = 128; st > 0; st >>= 1) { if (tid < st) red[tid] += red[tid + st]; __syncthreads(); }
    if (tid == 0) {
        float avg_ent = -red[0];
        float se = scal[3] * (1.f / 4096.f);
        float vq = scal[2] * (1.f / 1048576.f);
        out[1048576] = vq;
        out[1048577] = 0.25f * vq;
        out[1048578] = 0.1f * (se - avg_ent);
        out[1048579] = scal[0] * (1.f / 4096.f);
        out[1048580] = scal[1] * (1.f / 4096.f);
    }
}

// ---------------- host ----------------
extern "C" void kernel_launch(void* const* d_in, const int* in_sizes, int n_in,
                              void* d_out, int out_size, void* d_ws, size_t ws_size,
                              hipStream_t stream) {
    const float* z  = (const float*)d_in[0];
    const float* wk = (const float*)d_in[1];
    const float* wg = (const float*)d_in[2];
    float* out = (float*)d_out;

    char* ws = (char*)d_ws;
    size_t off = 0;
    auto alloc = [&](size_t bytes) {
        void* p = ws + off;
        off += (bytes + 255) & ~(size_t)255;
        return p;
    };
    float* enorm  = (float*)alloc((size_t)NE * KD * 4);        // 16.78 MB
    float* znorm  = (float*)alloc((size_t)T_TOK * KD * 4);     //  4.19 MB
    short* Es     = (short*)alloc((size_t)NE * K3 * 2);        // 25.17 MB
    short* Zs     = (short*)alloc((size_t)T_TOK * K3 * 2);     //  6.29 MB
    float* e2k    = (float*)alloc(NE * 4);
    float* e2g    = (float*)alloc(NE * 4);
    float* z2k    = (float*)alloc(T_TOK * 4);
    float* z2g    = (float*)alloc(T_TOK * 4);
    u64*   packed = (u64*)alloc(T_TOK * 8);
    float* m_arr  = (float*)alloc(T_TOK * 4);
    int*   idx_arr= (int*)alloc(T_TOK * 4);
    int*   ncand  = (int*)alloc(T_TOK * 4);
    float* candD  = (float*)alloc((size_t)T_TOK * CAP * 4);    // 16.78 MB
    int*   candN  = (int*)alloc((size_t)T_TOK * CAP * 4);      // 16.78 MB
    float* avg_num= (float*)alloc(NE * 4);
    float* scal   = (float*)alloc(8 * 4);                      // total ~86 MB

    vq_init_kernel<<<64, 256, 0, stream>>>(packed, avg_num, ncand, scal);
    norm_codes_kernel<<<NE, 256, 0, stream>>>(wk, wg, enorm, e2k, e2g, Es);
    norm_z_kernel<<<T_TOK, 256, 0, stream>>>(z, znorm, z2k, z2g, Zs);

    dim3 gg(NE / 128, T_TOK / 128);
    gemm_fused_kernel<<<gg, 256, 0, stream>>>(Zs, Es, z2k, z2g, e2k, e2g,
                                              packed, scal, candD, candN, ncand);
    argmin_kernel<<<16, 256, 0, stream>>>(packed, m_arr, idx_arr, out);
    zq_kernel<<<T_TOK, 256, 0, stream>>>(enorm, znorm, idx_arr, out, scal);
    token_entropy_kernel<<<T_TOK, 64, 0, stream>>>(candD, candN, ncand, m_arr, avg_num, scal);
    finalize_kernel<<<1, 256, 0, stream>>>(avg_num, scal, out);
}

// Round 3
// 548.242 us; speedup vs baseline: 2.6176x; 2.6176x over previous
//
#include <hip/hip_runtime.h>

// VectorQuantizer forward, MI355X. Split-bf16 MFMA GEMM (hi/lo, 3 products,
// K extended 256->768). Epilogue: argmin + d^2 sums + per-block online-softmax
// partials (exact entropy) + racy-shrinking-threshold candidate capture for
// avg_probs scatter. T=4096 tokens, NE=16384 codes.

#define T_TOK 4096
#define NE    16384
#define KD    256
#define K3    768          // 3x split-extended K
#define CAP   768          // candidate slots per token (avg_probs only)
#define DCUT  0.15f        // capture window above best-so-far global min

typedef __attribute__((ext_vector_type(8))) short bf16x8;
typedef __attribute__((ext_vector_type(4))) float f32x4;
typedef unsigned long long u64;

__device__ __forceinline__ short f2bf(float f) {
    unsigned u = __float_as_uint(f);
    u = (u + 0x7FFFu + ((u >> 16) & 1u)) >> 16;   // round-to-nearest-even
    return (short)u;
}
__device__ __forceinline__ float bf2f(short s) {
    return __uint_as_float(((unsigned)(unsigned short)s) << 16);
}

__device__ __forceinline__ void async_load16(const void* g, void* l) {
    __builtin_amdgcn_global_load_lds(
        (const __attribute__((address_space(1))) void*)g,
        (__attribute__((address_space(3))) void*)l, 16, 0, 0);
}

// ---------------- init ----------------
__global__ void vq_init_kernel(u64* __restrict__ packed, float* __restrict__ avg_num,
                               int* __restrict__ ncand, float* __restrict__ scal) {
    int i = blockIdx.x * 256 + threadIdx.x;
    if (i < T_TOK) packed[i] = ~0ull;
    if (i < NE)    avg_num[i] = 0.f;
    if (i < T_TOK) ncand[i] = 0;
    if (i < 8)     scal[i] = 0.f;
}

// ---------------- normalize codebooks -> enorm fp32, e2, Es (split bf16, -2x) ----------------
__global__ void norm_codes_kernel(const float* __restrict__ wk, const float* __restrict__ wg,
                                  float* __restrict__ enorm, float* __restrict__ e2k,
                                  float* __restrict__ e2g, short* __restrict__ Es) {
    int n = blockIdx.x, c = threadIdx.x;
    int lane = c & 63, w = c >> 6;
    float x = (c < 64) ? wk[n * 64 + c] : wg[n * 192 + (c - 64)];
    float s = x * x;
#pragma unroll
    for (int m = 1; m < 64; m <<= 1) s += __shfl_xor(s, m, 64);
    __shared__ float ws4[4];
    if (lane == 0) ws4[w] = s;
    __syncthreads();
    float sk = ws4[0], sg = ws4[1] + ws4[2] + ws4[3];
    float nk = fmaxf(sqrtf(sk), 1e-12f), ng = fmaxf(sqrtf(sg), 1e-12f);
    float y = x / ((c < 64) ? nk : ng);
    enorm[(size_t)n * KD + c] = y;
    if (c == 0) { e2k[n] = sk / (nk * nk); e2g[n] = sg / (ng * ng); }
    short h = f2bf(y);          float hf = bf2f(h);
    short l = f2bf(y - hf);     float lf = bf2f(l);
    short sh = f2bf(-2.f * hf), sl = f2bf(-2.f * lf);   // exact scaling
    short* Er = Es + (size_t)n * K3;
    if (c < 64) { Er[c] = sh; Er[64 + c] = sl; Er[128 + c] = sh; }
    else { int cc = c - 64; Er[192 + cc] = sh; Er[384 + cc] = sl; Er[576 + cc] = sh; }
}

// ---------------- normalize z (NCHW->token) -> znorm fp32, z2, Zs (split bf16) ----------------
__global__ void norm_z_kernel(const float* __restrict__ z, float* __restrict__ znorm,
                              float* __restrict__ z2k, float* __restrict__ z2g,
                              short* __restrict__ Zs) {
    int t = blockIdx.x, c = threadIdx.x;
    int lane = c & 63, w = c >> 6;
    int b = t >> 10, hw = t & 1023;
    float x = z[((size_t)b * 256 + c) * 1024 + hw];
    float s = x * x;
#pragma unroll
    for (int m = 1; m < 64; m <<= 1) s += __shfl_xor(s, m, 64);
    __shared__ float ws4[4];
    if (lane == 0) ws4[w] = s;
    __syncthreads();
    float sk = ws4[0], sg = ws4[1] + ws4[2] + ws4[3];
    float nk = fmaxf(sqrtf(sk), 1e-12f), ng = fmaxf(sqrtf(sg), 1e-12f);
    float y = x / ((c < 64) ? nk : ng);
    znorm[(size_t)t * KD + c] = y;
    if (c == 0) { z2k[t] = sk / (nk * nk); z2g[t] = sg / (ng * ng); }
    short h = f2bf(y);      float hf = bf2f(h);
    short l = f2bf(y - hf);
    short* Zr = Zs + (size_t)t * K3;
    if (c < 64) { Zr[c] = h; Zr[64 + c] = h; Zr[128 + c] = l; }
    else { int cc = c - 64; Zr[192 + cc] = h; Zr[384 + cc] = h; Zr[576 + cc] = l; }
}

// ---------------- fused MFMA GEMM ----------------
__global__ __launch_bounds__(256, 2)
void gemm_fused_kernel(const short* __restrict__ Zs, const short* __restrict__ Es,
                       const float* __restrict__ z2k, const float* __restrict__ z2g,
                       const float* __restrict__ e2k, const float* __restrict__ e2g,
                       u64* __restrict__ packed, float* __restrict__ scal,
                       float* __restrict__ part_m, float* __restrict__ part_z,
                       float* __restrict__ part_w,
                       float* __restrict__ candD, int* __restrict__ candN,
                       int* __restrict__ ncand) {
    __shared__ __align__(16) short As[128 * 64];   // [token_row][k] 64 bf16/row
    __shared__ __align__(16) short Bs[128 * 64];   // [code_row][k]
    const int tid = threadIdx.x;
    const int lane = tid & 63, wid = tid >> 6;
    const int wm = wid >> 1, wn = wid & 1;         // wave tile: 64(tok) x 64(code)
    const int n0 = blockIdx.x * 128, t0 = blockIdx.y * 128;

    f32x4 acck[4][4], accg[4][4];
#pragma unroll
    for (int bi = 0; bi < 4; ++bi)
#pragma unroll
        for (int bj = 0; bj < 4; ++bj) {
            f32x4 zz = {0.f, 0.f, 0.f, 0.f};
            acck[bi][bj] = zz; accg[bi][bj] = zz;
        }

    auto stage = [&](int k0) {
        const int rb0 = wid * 32;
#pragma unroll
        for (int c2 = 0; c2 < 4; ++c2) {
            int rb = rb0 + c2 * 8;
            int row = rb + (lane >> 3);
            int q = (lane & 7) ^ (lane >> 3);   // XOR-quad swizzle (rb%8==0)
            async_load16(Zs + (size_t)(t0 + row) * K3 + k0 + q * 8, &As[rb * 64]);
            async_load16(Es + (size_t)(n0 + row) * K3 + k0 + q * 8, &Bs[rb * 64]);
        }
    };
    auto compute_half = [&](f32x4 (&acc)[4][4], int s) {
        bf16x8 af[4], bfv[4];
#pragma unroll
        for (int bi = 0; bi < 4; ++bi) {
            int arow = wm * 64 + bi * 16 + (lane & 15);
            int q = ((s << 2) | (lane >> 4)) ^ (arow & 7);
            af[bi] = *reinterpret_cast<const bf16x8*>(&As[arow * 64 + q * 8]);
        }
#pragma unroll
        for (int bj = 0; bj < 4; ++bj) {
            int brow = wn * 64 + bj * 16 + (lane & 15);
            int q = ((s << 2) | (lane >> 4)) ^ (brow & 7);
            bfv[bj] = *reinterpret_cast<const bf16x8*>(&Bs[brow * 64 + q * 8]);
        }
#pragma unroll
        for (int bi = 0; bi < 4; ++bi)
#pragma unroll
            for (int bj = 0; bj < 4; ++bj)
                acc[bi][bj] = __builtin_amdgcn_mfma_f32_16x16x32_bf16(
                    af[bi], bfv[bj], acc[bi][bj], 0, 0, 0);
    };

    int k0 = 0;
    for (int r = 0; r < 3; ++r) {              // k-part -> acc = -2*dot_k
        stage(k0); __syncthreads();
        compute_half(acck, 0); compute_half(acck, 1);
        __syncthreads(); k0 += 64;
    }
    for (int r = 0; r < 9; ++r) {              // g-part -> acc = -2*dot_g
        stage(k0); __syncthreads();
        compute_half(accg, 0); compute_half(accg, 1);
        __syncthreads(); k0 += 64;
    }

    // ---- epilogue ----
    // LDS overlays on As (16 KB):
    char* lds = (char*)As;
    u64*   tokmin = (u64*)lds;                 // [128][2]   2048 B
    float* bmf    = (float*)(lds + 2048);      // [128] block-level m = -100*blockmin   512 B
    float* bthr   = (float*)(lds + 2560);      // [128] capture threshold (d units)     512 B
    float* pzw    = (float*)(lds + 3072);      // [128][2 wn][2 zw]                    2048 B

    float e2kv[4], e2gv[4];
#pragma unroll
    for (int bj = 0; bj < 4; ++bj) {
        int n = n0 + wn * 64 + bj * 16 + (lane & 15);
        e2kv[bj] = e2k[n]; e2gv[bj] = e2g[n];
    }
    float sdk2 = 0.f, sdg2 = 0.f;

    // pass 1: per-token wave-local packed min (d,n) + d^2 sums
#pragma unroll
    for (int bi = 0; bi < 4; ++bi) {
        u64 pmin[4] = {~0ull, ~0ull, ~0ull, ~0ull};
#pragma unroll
        for (int reg = 0; reg < 4; ++reg) {
            int t = t0 + wm * 64 + bi * 16 + (lane >> 4) * 4 + reg;
            float zk2 = z2k[t], zg2 = z2g[t];
#pragma unroll
            for (int bj = 0; bj < 4; ++bj) {
                float dk = zk2 + e2kv[bj] + acck[bi][bj][reg];
                float dg = zg2 + e2gv[bj] + accg[bi][bj][reg];
                float d = dk + dg;
                sdk2 = fmaf(dk, dk, sdk2);
                sdg2 = fmaf(dg, dg, sdg2);
                int n = n0 + wn * 64 + bj * 16 + (lane & 15);
                u64 pv = (((u64)__float_as_uint(d)) << 32) | (unsigned)n;
                if (pv < pmin[reg]) pmin[reg] = pv;
            }
        }
#pragma unroll
        for (int m = 1; m < 16; m <<= 1)
#pragma unroll
            for (int reg = 0; reg < 4; ++reg) {
                u64 o = __shfl_xor(pmin[reg], m, 64);
                if (o < pmin[reg]) pmin[reg] = o;
            }
        if ((lane & 15) == 0) {
#pragma unroll
            for (int reg = 0; reg < 4; ++reg) {
                int tl = wm * 64 + bi * 16 + (lane >> 4) * 4 + reg;
                tokmin[tl * 2 + wn] = pmin[reg];
            }
        }
    }
    __syncthreads();

    // owner step: block min -> global atomicMin (returns old => best-so-far)
    if (tid < 128) {
        int tl = tid;
        u64 bm = tokmin[tl * 2], b1 = tokmin[tl * 2 + 1];
        if (b1 < bm) bm = b1;
        u64 old = atomicMin(&packed[t0 + tl], bm);
        u64 gb = (old < bm) ? old : bm;
        float d_bmin = __uint_as_float((unsigned)(bm >> 32));
        bmf[tl] = -100.f * d_bmin;                              // block-level softmax max
        bthr[tl] = __uint_as_float((unsigned)(gb >> 32)) + DCUT; // global-ish capture thr
    }
    __syncthreads();

    // pass B: block-level softmax partials + candidate capture
#pragma unroll
    for (int bi = 0; bi < 4; ++bi) {
        float ez[4] = {0.f, 0.f, 0.f, 0.f}, ew[4] = {0.f, 0.f, 0.f, 0.f};
#pragma unroll
        for (int reg = 0; reg < 4; ++reg) {
            int tl = wm * 64 + bi * 16 + (lane >> 4) * 4 + reg;
            int t = t0 + tl;
            float m_b = bmf[tl], thr = bthr[tl];
            float zk2 = z2k[t], zg2 = z2g[t];
#pragma unroll
            for (int bj = 0; bj < 4; ++bj) {
                float dk = zk2 + e2kv[bj] + acck[bi][bj][reg];
                float dg = zg2 + e2gv[bj] + accg[bi][bj][reg];
                float d = dk + dg;
                float a = -100.f * d;
                float e = __expf(a - m_b);
                ez[reg] += e;
                ew[reg] = fmaf(a, e, ew[reg]);
                if (d <= thr) {
                    int pos = atomicAdd(&ncand[t], 1);
                    if (pos < CAP) {
                        candD[(size_t)t * CAP + pos] = d;
                        candN[(size_t)t * CAP + pos] = n0 + wn * 64 + bj * 16 + (lane & 15);
                    }
                }
            }
        }
#pragma unroll
        for (int m = 1; m < 16; m <<= 1)
#pragma unroll
            for (int reg = 0; reg < 4; ++reg) {
                ez[reg] += __shfl_xor(ez[reg], m, 64);
                ew[reg] += __shfl_xor(ew[reg], m, 64);
            }
        if ((lane & 15) == 0) {
#pragma unroll
            for (int reg = 0; reg < 4; ++reg) {
                int tl = wm * 64 + bi * 16 + (lane >> 4) * 4 + reg;
                pzw[(tl * 2 + wn) * 2 + 0] = ez[reg];
                pzw[(tl * 2 + wn) * 2 + 1] = ew[reg];
            }
        }
    }
    __syncthreads();

    // owner step 2: write per-block partials (coalesced)
    if (tid < 128) {
        int tl = tid;
        size_t o = (size_t)blockIdx.x * T_TOK + t0 + tl;
        part_m[o] = bmf[tl];
        part_z[o] = pzw[tl * 4 + 0] + pzw[tl * 4 + 2];
        part_w[o] = pzw[tl * 4 + 1] + pzw[tl * 4 + 3];
    }
    __syncthreads();

    // block-reduce d^2 partial sums
    float* red = (float*)As;
    red[tid] = sdk2; __syncthreads();
    for (int s = 128; s > 0; s >>= 1) { if (tid < s) red[tid] += red[tid + s]; __syncthreads(); }
    if (tid == 0) atomicAdd(&scal[0], red[0]);
    __syncthreads();
    red[tid] = sdg2; __syncthreads();
    for (int s = 128; s > 0; s >>= 1) { if (tid < s) red[tid] += red[tid + s]; __syncthreads(); }
    if (tid == 0) atomicAdd(&scal[1], red[0]);
}

// ---------------- combine: exact per-token softmax stats + idx unpack ----------------
__global__ void combine_kernel(const float* __restrict__ part_m, const float* __restrict__ part_z,
                               const float* __restrict__ part_w, const u64* __restrict__ packed,
                               float* __restrict__ m_arr, float* __restrict__ Z_arr,
                               int* __restrict__ idx_arr, float* __restrict__ out,
                               float* __restrict__ scal) {
    int lane = threadIdx.x;                 // 64
    int t = blockIdx.x * 64 + lane;
    float m = -3.0e38f, Z = 0.f, W = 0.f;
    for (int nb = 0; nb < NE / 128; ++nb) {
        size_t o = (size_t)nb * T_TOK + t;
        float mb = part_m[o], zb = part_z[o], wb = part_w[o];
        if (mb > m) { float s = __expf(m - mb); Z *= s; W *= s; m = mb; }
        float s2 = __expf(mb - m);
        Z = fmaf(zb, s2, Z); W = fmaf(wb, s2, W);
    }
    m_arr[t] = m; Z_arr[t] = Z;
    u64 pv = packed[t];
    int idx = (int)(pv & 0xFFFFFFFFull);
    idx_arr[t] = idx;
    out[1048581 + t] = (float)idx;
    float ent = m + logf(Z) - W / Z;        // -sum p log p for this token
#pragma unroll
    for (int mm = 1; mm < 64; mm <<= 1) ent += __shfl_xor(ent, mm, 64);
    if (lane == 0) atomicAdd(&scal[3], ent);
}

// ---------------- z_q gather + vq loss ----------------
__global__ void zq_kernel(const float* __restrict__ enorm, const float* __restrict__ znorm,
                          const int* __restrict__ idx_arr,
                          float* __restrict__ out, float* __restrict__ scal) {
    int t = blockIdx.x, c = threadIdx.x;
    int b = t >> 10, hw = t & 1023;
    float q = enorm[(size_t)idx_arr[t] * KD + c];
    float zc = znorm[(size_t)t * KD + c];
    out[((size_t)b * 256 + c) * 1024 + hw] = q;
    float df = q - zc;
    __shared__ float red[256];
    red[c] = df * df;
    __syncthreads();
    for (int s = 128; s > 0; s >>= 1) { if (c < s) red[c] += red[c + s]; __syncthreads(); }
    if (c == 0) atomicAdd(&scal[2], red[0]);
}

// ---------------- avg_probs scatter from candidates ----------------
__global__ void avg_scatter_kernel(const float* __restrict__ candD, const int* __restrict__ candN,
                                   const int* __restrict__ ncand, const float* __restrict__ m_arr,
                                   const float* __restrict__ Z_arr, float* __restrict__ avg_num) {
    int t = blockIdx.x, lane = threadIdx.x;  // 64
    int nc = min(ncand[t], CAP);
    float m = m_arr[t], Z = Z_arr[t];
    for (int i = lane; i < nc; i += 64) {
        float a = -100.f * candD[(size_t)t * CAP + i];
        atomicAdd(&avg_num[candN[(size_t)t * CAP + i]], __expf(a - m) / Z);
    }
}

// ---------------- final scalars ----------------
__global__ void finalize_kernel(const float* __restrict__ avg_num, const float* __restrict__ scal,
                                float* __restrict__ out) {
    __shared__ float red[256];
    int tid = threadIdx.x;
    float s = 0.f;
    for (int n = tid; n < NE; n += 256) {
        float avg = avg_num[n] * (1.f / 4096.f);
        s += avg * logf(avg + 1e-5f);
    }
    red[tid] = s;
    __syncthreads();
    for (int st = 128; st > 0; st >>= 1) { if (tid < st) red[tid] += red[tid + st]; __syncthreads(); }
    if (tid == 0) {
        float avg_ent = -red[0];
        float se = scal[3] * (1.f / 4096.f);
        float vq = scal[2] * (1.f / 1048576.f);
        out[1048576] = vq;
        out[1048577] = 0.25f * vq;
        out[1048578] = 0.1f * (se - avg_ent);
        out[1048579] = scal[0] * (1.f / 4096.f);
        out[1048580] = scal[1] * (1.f / 4096.f);
    }
}

// ---------------- host ----------------
extern "C" void kernel_launch(void* const* d_in, const int* in_sizes, int n_in,
                              void* d_out, int out_size, void* d_ws, size_t ws_size,
                              hipStream_t stream) {
    const float* z  = (const float*)d_in[0];
    const float* wk = (const float*)d_in[1];
    const float* wg = (const float*)d_in[2];
    float* out = (float*)d_out;

    char* ws = (char*)d_ws;
    size_t off = 0;
    auto alloc = [&](size_t bytes) {
        void* p = ws + off;
        off += (bytes + 255) & ~(size_t)255;
        return p;
    };
    float* enorm  = (float*)alloc((size_t)NE * KD * 4);        // 16.78 MB
    float* znorm  = (float*)alloc((size_t)T_TOK * KD * 4);     //  4.19 MB
    short* Es     = (short*)alloc((size_t)NE * K3 * 2);        // 25.17 MB
    short* Zs     = (short*)alloc((size_t)T_TOK * K3 * 2);     //  6.29 MB
    float* e2k    = (float*)alloc(NE * 4);
    float* e2g    = (float*)alloc(NE * 4);
    float* z2k    = (float*)alloc(T_TOK * 4);
    float* z2g    = (float*)alloc(T_TOK * 4);
    u64*   packed = (u64*)alloc(T_TOK * 8);
    float* m_arr  = (float*)alloc(T_TOK * 4);
    float* Z_arr  = (float*)alloc(T_TOK * 4);
    int*   idx_arr= (int*)alloc(T_TOK * 4);
    int*   ncand  = (int*)alloc(T_TOK * 4);
    float* part_m = (float*)alloc((size_t)(NE / 128) * T_TOK * 4);  // 2.10 MB
    float* part_z = (float*)alloc((size_t)(NE / 128) * T_TOK * 4);  // 2.10 MB
    float* part_w = (float*)alloc((size_t)(NE / 128) * T_TOK * 4);  // 2.10 MB
    float* candD  = (float*)alloc((size_t)T_TOK * CAP * 4);    // 12.58 MB
    int*   candN  = (int*)alloc((size_t)T_TOK * CAP * 4);      // 12.58 MB
    float* avg_num= (float*)alloc(NE * 4);
    float* scal   = (float*)alloc(8 * 4);                      // total ~84 MB

    vq_init_kernel<<<64, 256, 0, stream>>>(packed, avg_num, ncand, scal);
    norm_codes_kernel<<<NE, 256, 0, stream>>>(wk, wg, enorm, e2k, e2g, Es);
    norm_z_kernel<<<T_TOK, 256, 0, stream>>>(z, znorm, z2k, z2g, Zs);

    dim3 gg(NE / 128, T_TOK / 128);
    gemm_fused_kernel<<<gg, 256, 0, stream>>>(Zs, Es, z2k, z2g, e2k, e2g,
                                              packed, scal, part_m, part_z, part_w,
                                              candD, candN, ncand);
    combine_kernel<<<T_TOK / 64, 64, 0, stream>>>(part_m, part_z, part_w, packed,
                                                  m_arr, Z_arr, idx_arr, out, scal);
    zq_kernel<<<T_TOK, 256, 0, stream>>>(enorm, znorm, idx_arr, out, scal);
    avg_scatter_kernel<<<T_TOK, 64, 0, stream>>>(candD, candN, ncand, m_arr, Z_arr, avg_num);
    finalize_kernel<<<1, 256, 0, stream>>>(avg_num, scal, out);
}

// Round 4
// 535.605 us; speedup vs baseline: 2.6793x; 1.0236x over previous
//
#include <hip/hip_runtime.h>

// VectorQuantizer forward, MI355X. Split-bf16 MFMA GEMM (hi/lo, 3 products,
// K extended 256->768), SINGLE accumulator + bf16 dk stash (mid-epilogue) for
// the d^2-norm split. Epilogue: argmin + per-block online-softmax partials
// (exact entropy) + racy-shrinking-threshold candidate capture.
// T=4096 tokens, NE=16384 codes.

#define T_TOK 4096
#define NE    16384
#define KD    256
#define K3    768          // 3x split-extended K
#define CAP   768          // candidate slots per token (avg_probs only)
#define DCUT  0.15f        // capture window above best-so-far global min

typedef __attribute__((ext_vector_type(8))) short bf16x8;
typedef __attribute__((ext_vector_type(4))) float f32x4;
typedef unsigned long long u64;

__device__ __forceinline__ short f2bf(float f) {
    unsigned u = __float_as_uint(f);
    u = (u + 0x7FFFu + ((u >> 16) & 1u)) >> 16;   // round-to-nearest-even
    return (short)u;
}
__device__ __forceinline__ float bf2f(short s) {
    return __uint_as_float(((unsigned)(unsigned short)s) << 16);
}

__device__ __forceinline__ void async_load16(const void* g, void* l) {
    __builtin_amdgcn_global_load_lds(
        (const __attribute__((address_space(1))) void*)g,
        (__attribute__((address_space(3))) void*)l, 16, 0, 0);
}

// ---------------- init ----------------
__global__ void vq_init_kernel(u64* __restrict__ packed, float* __restrict__ avg_num,
                               int* __restrict__ ncand, float* __restrict__ scal) {
    int i = blockIdx.x * 256 + threadIdx.x;
    if (i < T_TOK) packed[i] = ~0ull;
    if (i < NE)    avg_num[i] = 0.f;
    if (i < T_TOK) ncand[i] = 0;
    if (i < 8)     scal[i] = 0.f;
}

// ---------------- normalize codebooks -> enorm fp32, e2k/e2s, Es (split bf16, -2x) --------
__global__ void norm_codes_kernel(const float* __restrict__ wk, const float* __restrict__ wg,
                                  float* __restrict__ enorm, float* __restrict__ e2k,
                                  float* __restrict__ e2s, short* __restrict__ Es) {
    int n = blockIdx.x, c = threadIdx.x;
    int lane = c & 63, w = c >> 6;
    float x = (c < 64) ? wk[n * 64 + c] : wg[n * 192 + (c - 64)];
    float s = x * x;
#pragma unroll
    for (int m = 1; m < 64; m <<= 1) s += __shfl_xor(s, m, 64);
    __shared__ float ws4[4];
    if (lane == 0) ws4[w] = s;
    __syncthreads();
    float sk = ws4[0], sg = ws4[1] + ws4[2] + ws4[3];
    float nk = fmaxf(sqrtf(sk), 1e-12f), ng = fmaxf(sqrtf(sg), 1e-12f);
    float y = x / ((c < 64) ? nk : ng);
    enorm[(size_t)n * KD + c] = y;
    if (c == 0) {
        float ek2 = sk / (nk * nk), eg2 = sg / (ng * ng);
        e2k[n] = ek2; e2s[n] = ek2 + eg2;
    }
    short h = f2bf(y);          float hf = bf2f(h);
    short l = f2bf(y - hf);     float lf = bf2f(l);
    short sh = f2bf(-2.f * hf), sl = f2bf(-2.f * lf);   // exact scaling
    short* Er = Es + (size_t)n * K3;
    if (c < 64) { Er[c] = sh; Er[64 + c] = sl; Er[128 + c] = sh; }
    else { int cc = c - 64; Er[192 + cc] = sh; Er[384 + cc] = sl; Er[576 + cc] = sh; }
}

// ---------------- normalize z (NCHW->token) -> znorm fp32, z2k/z2s, Zs (split bf16) -------
__global__ void norm_z_kernel(const float* __restrict__ z, float* __restrict__ znorm,
                              float* __restrict__ z2k, float* __restrict__ z2s,
                              short* __restrict__ Zs) {
    int t = blockIdx.x, c = threadIdx.x;
    int lane = c & 63, w = c >> 6;
    int b = t >> 10, hw = t & 1023;
    float x = z[((size_t)b * 256 + c) * 1024 + hw];
    float s = x * x;
#pragma unroll
    for (int m = 1; m < 64; m <<= 1) s += __shfl_xor(s, m, 64);
    __shared__ float ws4[4];
    if (lane == 0) ws4[w] = s;
    __syncthreads();
    float sk = ws4[0], sg = ws4[1] + ws4[2] + ws4[3];
    float nk = fmaxf(sqrtf(sk), 1e-12f), ng = fmaxf(sqrtf(sg), 1e-12f);
    float y = x / ((c < 64) ? nk : ng);
    znorm[(size_t)t * KD + c] = y;
    if (c == 0) {
        float zk2 = sk / (nk * nk), zg2 = sg / (ng * ng);
        z2k[t] = zk2; z2s[t] = zk2 + zg2;
    }
    short h = f2bf(y);      float hf = bf2f(h);
    short l = f2bf(y - hf);
    short* Zr = Zs + (size_t)t * K3;
    if (c < 64) { Zr[c] = h; Zr[64 + c] = h; Zr[128 + c] = l; }
    else { int cc = c - 64; Zr[192 + cc] = h; Zr[384 + cc] = h; Zr[576 + cc] = l; }
}

// ---------------- fused MFMA GEMM ----------------
__global__ __launch_bounds__(256, 4)
void gemm_fused_kernel(const short* __restrict__ Zs, const short* __restrict__ Es,
                       const float* __restrict__ z2k, const float* __restrict__ e2k,
                       const float* __restrict__ z2s, const float* __restrict__ e2s,
                       u64* __restrict__ packed, float* __restrict__ scal,
                       float* __restrict__ part_m, float* __restrict__ part_z,
                       float* __restrict__ part_w,
                       float* __restrict__ candD, int* __restrict__ candN,
                       int* __restrict__ ncand) {
    __shared__ __align__(16) short As[128 * 64];   // [token_row][k] 64 bf16/row
    __shared__ __align__(16) short Bs[128 * 64];   // [code_row][k]
    const int tid = threadIdx.x;
    const int lane = tid & 63, wid = tid >> 6;
    const int wm = wid >> 1, wn = wid & 1;         // wave tile: 64(tok) x 64(code)
    const int n0 = blockIdx.x * 128, t0 = blockIdx.y * 128;

    f32x4 acc[4][4];
#pragma unroll
    for (int bi = 0; bi < 4; ++bi)
#pragma unroll
        for (int bj = 0; bj < 4; ++bj) {
            f32x4 zz = {0.f, 0.f, 0.f, 0.f};
            acc[bi][bj] = zz;
        }

    auto stage = [&](int k0) {
        const int rb0 = wid * 32;
#pragma unroll
        for (int c2 = 0; c2 < 4; ++c2) {
            int rb = rb0 + c2 * 8;
            int row = rb + (lane >> 3);
            int q = (lane & 7) ^ (lane >> 3);   // XOR-quad swizzle (rb%8==0)
            async_load16(Zs + (size_t)(t0 + row) * K3 + k0 + q * 8, &As[rb * 64]);
            async_load16(Es + (size_t)(n0 + row) * K3 + k0 + q * 8, &Bs[rb * 64]);
        }
    };
    auto compute_half = [&](int s) {
        bf16x8 bfv[4];
#pragma unroll
        for (int bj = 0; bj < 4; ++bj) {
            int brow = wn * 64 + bj * 16 + (lane & 15);
            int q = ((s << 2) | (lane >> 4)) ^ (brow & 7);
            bfv[bj] = *reinterpret_cast<const bf16x8*>(&Bs[brow * 64 + q * 8]);
        }
#pragma unroll
        for (int bi = 0; bi < 4; ++bi) {
            int arow = wm * 64 + bi * 16 + (lane & 15);
            int q = ((s << 2) | (lane >> 4)) ^ (arow & 7);
            bf16x8 af = *reinterpret_cast<const bf16x8*>(&As[arow * 64 + q * 8]);
#pragma unroll
            for (int bj = 0; bj < 4; ++bj)
                acc[bi][bj] = __builtin_amdgcn_mfma_f32_16x16x32_bf16(
                    af, bfv[bj], acc[bi][bj], 0, 0, 0);
        }
    };

    int k0 = 0;
    for (int r = 0; r < 3; ++r) {              // k-part: acc = -2*dot_k
        stage(k0); __syncthreads();
        compute_half(0); compute_half(1);
        __syncthreads(); k0 += 64;
    }

    // ---- mid-epilogue: dk = z2k + e2k + acc; stash bf16, accumulate sum(dk^2) ----
    float sdk2 = 0.f;
    unsigned dkp[4][4][2];
    {
        float e2kv[4];
#pragma unroll
        for (int bj = 0; bj < 4; ++bj)
            e2kv[bj] = e2k[n0 + wn * 64 + bj * 16 + (lane & 15)];
#pragma unroll
        for (int bi = 0; bi < 4; ++bi) {
            f32x4 z4 = *reinterpret_cast<const f32x4*>(
                &z2k[t0 + wm * 64 + bi * 16 + (lane >> 4) * 4]);
#pragma unroll
            for (int reg = 0; reg < 4; ++reg) {
#pragma unroll
                for (int bj = 0; bj < 4; ++bj) {
                    float dk = z4[reg] + e2kv[bj] + acc[bi][bj][reg];
                    sdk2 = fmaf(dk, dk, sdk2);
                    unsigned hb = (unsigned)(unsigned short)f2bf(dk);
                    if ((reg & 1) == 0) dkp[bi][bj][reg >> 1] = hb;
                    else                dkp[bi][bj][reg >> 1] |= hb << 16;
                }
            }
        }
    }

    for (int r = 0; r < 9; ++r) {              // g-part: acc += -2*dot_g
        stage(k0); __syncthreads();
        compute_half(0); compute_half(1);
        __syncthreads(); k0 += 64;
    }

    // ---- final epilogue ----
    char* lds = (char*)As;
    u64*   tokmin = (u64*)lds;                 // [128][2]   2048 B
    float* bmf    = (float*)(lds + 2048);      // [128]       512 B
    float* bthr   = (float*)(lds + 2560);      // [128]       512 B
    float* pzw    = (float*)(lds + 3072);      // [128][2][2] 2048 B

    float e2sv[4];
#pragma unroll
    for (int bj = 0; bj < 4; ++bj)
        e2sv[bj] = e2s[n0 + wn * 64 + bj * 16 + (lane & 15)];

    float sdg2 = 0.f;

    // pass 1: per-token wave-local packed min (d,n) + sum(dg^2) via dg = d - dk
#pragma unroll
    for (int bi = 0; bi < 4; ++bi) {
        u64 pmin[4] = {~0ull, ~0ull, ~0ull, ~0ull};
        f32x4 z4 = *reinterpret_cast<const f32x4*>(
            &z2s[t0 + wm * 64 + bi * 16 + (lane >> 4) * 4]);
#pragma unroll
        for (int reg = 0; reg < 4; ++reg) {
#pragma unroll
            for (int bj = 0; bj < 4; ++bj) {
                float d = z4[reg] + e2sv[bj] + acc[bi][bj][reg];
                float dkf = bf2f((short)(dkp[bi][bj][reg >> 1] >> ((reg & 1) * 16)));
                float dg = d - dkf;
                sdg2 = fmaf(dg, dg, sdg2);
                int n = n0 + wn * 64 + bj * 16 + (lane & 15);
                u64 pv = (((u64)__float_as_uint(d)) << 32) | (unsigned)n;
                if (pv < pmin[reg]) pmin[reg] = pv;
            }
        }
#pragma unroll
        for (int m = 1; m < 16; m <<= 1)
#pragma unroll
            for (int reg = 0; reg < 4; ++reg) {
                u64 o = __shfl_xor(pmin[reg], m, 64);
                if (o < pmin[reg]) pmin[reg] = o;
            }
        if ((lane & 15) == 0) {
#pragma unroll
            for (int reg = 0; reg < 4; ++reg) {
                int tl = wm * 64 + bi * 16 + (lane >> 4) * 4 + reg;
                tokmin[tl * 2 + wn] = pmin[reg];
            }
        }
    }
    __syncthreads();

    // owner step: block min -> global atomicMin (returns old => best-so-far)
    if (tid < 128) {
        int tl = tid;
        u64 bm = tokmin[tl * 2], b1 = tokmin[tl * 2 + 1];
        if (b1 < bm) bm = b1;
        u64 old = atomicMin(&packed[t0 + tl], bm);
        u64 gb = (old < bm) ? old : bm;
        float d_bmin = __uint_as_float((unsigned)(bm >> 32));
        bmf[tl] = -100.f * d_bmin;
        bthr[tl] = __uint_as_float((unsigned)(gb >> 32)) + DCUT;
    }
    __syncthreads();

    // pass 2: block-level softmax partials + candidate capture
#pragma unroll
    for (int bi = 0; bi < 4; ++bi) {
        float ez[4] = {0.f, 0.f, 0.f, 0.f}, ew[4] = {0.f, 0.f, 0.f, 0.f};
        f32x4 z4 = *reinterpret_cast<const f32x4*>(
            &z2s[t0 + wm * 64 + bi * 16 + (lane >> 4) * 4]);
#pragma unroll
        for (int reg = 0; reg < 4; ++reg) {
            int tl = wm * 64 + bi * 16 + (lane >> 4) * 4 + reg;
            int t = t0 + tl;
            float m_b = bmf[tl], thr = bthr[tl];
#pragma unroll
            for (int bj = 0; bj < 4; ++bj) {
                float d = z4[reg] + e2sv[bj] + acc[bi][bj][reg];
                float a = -100.f * d;
                float e = __expf(a - m_b);
                ez[reg] += e;
                ew[reg] = fmaf(a, e, ew[reg]);
                if (d <= thr) {
                    int pos = atomicAdd(&ncand[t], 1);
                    if (pos < CAP) {
                        candD[(size_t)t * CAP + pos] = d;
                        candN[(size_t)t * CAP + pos] = n0 + wn * 64 + bj * 16 + (lane & 15);
                    }
                }
            }
        }
#pragma unroll
        for (int m = 1; m < 16; m <<= 1)
#pragma unroll
            for (int reg = 0; reg < 4; ++reg) {
                ez[reg] += __shfl_xor(ez[reg], m, 64);
                ew[reg] += __shfl_xor(ew[reg], m, 64);
            }
        if ((lane & 15) == 0) {
#pragma unroll
            for (int reg = 0; reg < 4; ++reg) {
                int tl = wm * 64 + bi * 16 + (lane >> 4) * 4 + reg;
                pzw[(tl * 2 + wn) * 2 + 0] = ez[reg];
                pzw[(tl * 2 + wn) * 2 + 1] = ew[reg];
            }
        }
    }
    __syncthreads();

    // owner step 2: write per-block partials (coalesced)
    if (tid < 128) {
        int tl = tid;
        size_t o = (size_t)blockIdx.x * T_TOK + t0 + tl;
        part_m[o] = bmf[tl];
        part_z[o] = pzw[tl * 4 + 0] + pzw[tl * 4 + 2];
        part_w[o] = pzw[tl * 4 + 1] + pzw[tl * 4 + 3];
    }
    __syncthreads();

    // block-reduce d^2 partial sums
    float* red = (float*)As;
    red[tid] = sdk2; __syncthreads();
    for (int s = 128; s > 0; s >>= 1) { if (tid < s) red[tid] += red[tid + s]; __syncthreads(); }
    if (tid == 0) atomicAdd(&scal[0], red[0]);
    __syncthreads();
    red[tid] = sdg2; __syncthreads();
    for (int s = 128; s > 0; s >>= 1) { if (tid < s) red[tid] += red[tid + s]; __syncthreads(); }
    if (tid == 0) atomicAdd(&scal[1], red[0]);
}

// ---------------- combine: exact per-token softmax stats + idx unpack ----------------
__global__ void combine_kernel(const float* __restrict__ part_m, const float* __restrict__ part_z,
                               const float* __restrict__ part_w, const u64* __restrict__ packed,
                               float* __restrict__ m_arr, float* __restrict__ Z_arr,
                               int* __restrict__ idx_arr, float* __restrict__ out,
                               float* __restrict__ scal) {
    int lane = threadIdx.x;                 // 64
    int t = blockIdx.x * 64 + lane;
    float m = -3.0e38f, Z = 0.f, W = 0.f;
    for (int nb = 0; nb < NE / 128; ++nb) {
        size_t o = (size_t)nb * T_TOK + t;
        float mb = part_m[o], zb = part_z[o], wb = part_w[o];
        if (mb > m) { float s = __expf(m - mb); Z *= s; W *= s; m = mb; }
        float s2 = __expf(mb - m);
        Z = fmaf(zb, s2, Z); W = fmaf(wb, s2, W);
    }
    m_arr[t] = m; Z_arr[t] = Z;
    u64 pv = packed[t];
    int idx = (int)(pv & 0xFFFFFFFFull);
    idx_arr[t] = idx;
    out[1048581 + t] = (float)idx;
    float ent = m + logf(Z) - W / Z;        // -sum p log p for this token
#pragma unroll
    for (int mm = 1; mm < 64; mm <<= 1) ent += __shfl_xor(ent, mm, 64);
    if (lane == 0) atomicAdd(&scal[3], ent);
}

// ---------------- z_q gather + vq loss (LDS transpose, coalesced NCHW stores) --------
__global__ __launch_bounds__(256)
void zq_kernel(const float* __restrict__ enorm, const float* __restrict__ znorm,
               const int* __restrict__ idx_arr,
               float* __restrict__ out, float* __restrict__ scal) {
    __shared__ float q_lds[256][33];        // [c][token_local], padded
    __shared__ float red[256];
    int tid = threadIdx.x;
    int t0 = blockIdx.x * 32;               // 32 tokens per block, same b
    float sdq = 0.f;
    for (int tl = 0; tl < 32; ++tl) {
        int t = t0 + tl;
        float q = enorm[(size_t)idx_arr[t] * KD + tid];
        q_lds[tid][tl] = q;
        float zc = znorm[(size_t)t * KD + tid];
        float df = q - zc;
        sdq = fmaf(df, df, sdq);
    }
    __syncthreads();
    int b = t0 >> 10, hw0 = t0 & 1023;
    int cg = tid >> 5, hwl = tid & 31;
    for (int c0 = 0; c0 < 256; c0 += 8) {
        int c = c0 + cg;
        out[((size_t)(b * 256 + c)) * 1024 + hw0 + hwl] = q_lds[c][hwl];
    }
    red[tid] = sdq;
    __syncthreads();
    for (int s = 128; s > 0; s >>= 1) { if (tid < s) red[tid] += red[tid + s]; __syncthreads(); }
    if (tid == 0) atomicAdd(&scal[2], red[0]);
}

// ---------------- avg_probs scatter from candidates ----------------
__global__ void avg_scatter_kernel(const float* __restrict__ candD, const int* __restrict__ candN,
                                   const int* __restrict__ ncand, const float* __restrict__ m_arr,
                                   const float* __restrict__ Z_arr, float* __restrict__ avg_num) {
    int t = blockIdx.x, lane = threadIdx.x;  // 64
    int nc = min(ncand[t], CAP);
    float m = m_arr[t], Z = Z_arr[t];
    for (int i = lane; i < nc; i += 64) {
        float a = -100.f * candD[(size_t)t * CAP + i];
        atomicAdd(&avg_num[candN[(size_t)t * CAP + i]], __expf(a - m) / Z);
    }
}

// ---------------- final scalars ----------------
__global__ void finalize_kernel(const float* __restrict__ avg_num, const float* __restrict__ scal,
                                float* __restrict__ out) {
    __shared__ float red[256];
    int tid = threadIdx.x;
    float s = 0.f;
    for (int n = tid; n < NE; n += 256) {
        float avg = avg_num[n] * (1.f / 4096.f);
        s += avg * logf(avg + 1e-5f);
    }
    red[tid] = s;
    __syncthreads();
    for (int st = 128; st > 0; st >>= 1) { if (tid < st) red[tid] += red[tid + st]; __syncthreads(); }
    if (tid == 0) {
        float avg_ent = -red[0];
        float se = scal[3] * (1.f / 4096.f);
        float vq = scal[2] * (1.f / 1048576.f);
        out[1048576] = vq;
        out[1048577] = 0.25f * vq;
        out[1048578] = 0.1f * (se - avg_ent);
        out[1048579] = scal[0] * (1.f / 4096.f);
        out[1048580] = scal[1] * (1.f / 4096.f);
    }
}

// ---------------- host ----------------
extern "C" void kernel_launch(void* const* d_in, const int* in_sizes, int n_in,
                              void* d_out, int out_size, void* d_ws, size_t ws_size,
                              hipStream_t stream) {
    const float* z  = (const float*)d_in[0];
    const float* wk = (const float*)d_in[1];
    const float* wg = (const float*)d_in[2];
    float* out = (float*)d_out;

    char* ws = (char*)d_ws;
    size_t off = 0;
    auto alloc = [&](size_t bytes) {
        void* p = ws + off;
        off += (bytes + 255) & ~(size_t)255;
        return p;
    };
    float* enorm  = (float*)alloc((size_t)NE * KD * 4);        // 16.78 MB
    float* znorm  = (float*)alloc((size_t)T_TOK * KD * 4);     //  4.19 MB
    short* Es     = (short*)alloc((size_t)NE * K3 * 2);        // 25.17 MB
    short* Zs     = (short*)alloc((size_t)T_TOK * K3 * 2);     //  6.29 MB
    float* e2k    = (float*)alloc(NE * 4);
    float* e2s    = (float*)alloc(NE * 4);
    float* z2k    = (float*)alloc(T_TOK * 4);
    float* z2s    = (float*)alloc(T_TOK * 4);
    u64*   packed = (u64*)alloc(T_TOK * 8);
    float* m_arr  = (float*)alloc(T_TOK * 4);
    float* Z_arr  = (float*)alloc(T_TOK * 4);
    int*   idx_arr= (int*)alloc(T_TOK * 4);
    int*   ncand  = (int*)alloc(T_TOK * 4);
    float* part_m = (float*)alloc((size_t)(NE / 128) * T_TOK * 4);  // 2.10 MB
    float* part_z = (float*)alloc((size_t)(NE / 128) * T_TOK * 4);  // 2.10 MB
    float* part_w = (float*)alloc((size_t)(NE / 128) * T_TOK * 4);  // 2.10 MB
    float* candD  = (float*)alloc((size_t)T_TOK * CAP * 4);    // 12.58 MB
    int*   candN  = (int*)alloc((size_t)T_TOK * CAP * 4);      // 12.58 MB
    float* avg_num= (float*)alloc(NE * 4);
    float* scal   = (float*)alloc(8 * 4);                      // total ~84 MB

    vq_init_kernel<<<64, 256, 0, stream>>>(packed, avg_num, ncand, scal);
    norm_codes_kernel<<<NE, 256, 0, stream>>>(wk, wg, enorm, e2k, e2s, Es);
    norm_z_kernel<<<T_TOK, 256, 0, stream>>>(z, znorm, z2k, z2s, Zs);

    dim3 gg(NE / 128, T_TOK / 128);
    gemm_fused_kernel<<<gg, 256, 0, stream>>>(Zs, Es, z2k, e2k, z2s, e2s,
                                              packed, scal, part_m, part_z, part_w,
                                              candD, candN, ncand);
    combine_kernel<<<T_TOK / 64, 64, 0, stream>>>(part_m, part_z, part_w, packed,
                                                  m_arr, Z_arr, idx_arr, out, scal);
    zq_kernel<<<T_TOK / 32, 256, 0, stream>>>(enorm, znorm, idx_arr, out, scal);
    avg_scatter_kernel<<<T_TOK, 64, 0, stream>>>(candD, candN, ncand, m_arr, Z_arr, avg_num);
    finalize_kernel<<<1, 256, 0, stream>>>(avg_num, scal, out);
}

// Round 5
// 471.795 us; speedup vs baseline: 3.0417x; 1.1352x over previous
//
#include <hip/hip_runtime.h>

// VectorQuantizer forward, MI355X. Split-bf16 MFMA GEMM (hi/lo, 3 products,
// K extended 256->768), SINGLE accumulator + bf16 dk stash (mid-epilogue) for
// the d^2-norm split. Epilogue: argmin + per-block online-softmax partials
// (exact entropy) + racy-shrinking-threshold candidate capture.
// T=4096 tokens, NE=16384 codes.
// R5: launch_bounds (256,3) — (256,4) forced VGPR=64 and spilled ~1GB to
// scratch (R4: FETCH 700MB/WRITE 774MB). Grid dims swapped (x=token-block)
// for per-XCD Es-tile L2 reuse.

#define T_TOK 4096
#define NE    16384
#define KD    256
#define K3    768          // 3x split-extended K
#define CAP   768          // candidate slots per token (avg_probs only)
#define DCUT  0.15f        // capture window above best-so-far global min

typedef __attribute__((ext_vector_type(8))) short bf16x8;
typedef __attribute__((ext_vector_type(4))) float f32x4;
typedef unsigned long long u64;

__device__ __forceinline__ short f2bf(float f) {
    unsigned u = __float_as_uint(f);
    u = (u + 0x7FFFu + ((u >> 16) & 1u)) >> 16;   // round-to-nearest-even
    return (short)u;
}
__device__ __forceinline__ float bf2f(short s) {
    return __uint_as_float(((unsigned)(unsigned short)s) << 16);
}

__device__ __forceinline__ void async_load16(const void* g, void* l) {
    __builtin_amdgcn_global_load_lds(
        (const __attribute__((address_space(1))) void*)g,
        (__attribute__((address_space(3))) void*)l, 16, 0, 0);
}

// ---------------- init ----------------
__global__ void vq_init_kernel(u64* __restrict__ packed, float* __restrict__ avg_num,
                               int* __restrict__ ncand, float* __restrict__ scal) {
    int i = blockIdx.x * 256 + threadIdx.x;
    if (i < T_TOK) packed[i] = ~0ull;
    if (i < NE)    avg_num[i] = 0.f;
    if (i < T_TOK) ncand[i] = 0;
    if (i < 8)     scal[i] = 0.f;
}

// ---------------- normalize codebooks -> enorm fp32, e2k/e2s, Es (split bf16, -2x) --------
__global__ void norm_codes_kernel(const float* __restrict__ wk, const float* __restrict__ wg,
                                  float* __restrict__ enorm, float* __restrict__ e2k,
                                  float* __restrict__ e2s, short* __restrict__ Es) {
    int n = blockIdx.x, c = threadIdx.x;
    int lane = c & 63, w = c >> 6;
    float x = (c < 64) ? wk[n * 64 + c] : wg[n * 192 + (c - 64)];
    float s = x * x;
#pragma unroll
    for (int m = 1; m < 64; m <<= 1) s += __shfl_xor(s, m, 64);
    __shared__ float ws4[4];
    if (lane == 0) ws4[w] = s;
    __syncthreads();
    float sk = ws4[0], sg = ws4[1] + ws4[2] + ws4[3];
    float nk = fmaxf(sqrtf(sk), 1e-12f), ng = fmaxf(sqrtf(sg), 1e-12f);
    float y = x / ((c < 64) ? nk : ng);
    enorm[(size_t)n * KD + c] = y;
    if (c == 0) {
        float ek2 = sk / (nk * nk), eg2 = sg / (ng * ng);
        e2k[n] = ek2; e2s[n] = ek2 + eg2;
    }
    short h = f2bf(y);          float hf = bf2f(h);
    short l = f2bf(y - hf);     float lf = bf2f(l);
    short sh = f2bf(-2.f * hf), sl = f2bf(-2.f * lf);   // exact scaling
    short* Er = Es + (size_t)n * K3;
    if (c < 64) { Er[c] = sh; Er[64 + c] = sl; Er[128 + c] = sh; }
    else { int cc = c - 64; Er[192 + cc] = sh; Er[384 + cc] = sl; Er[576 + cc] = sh; }
}

// ---------------- normalize z (NCHW->token) -> znorm fp32, z2k/z2s, Zs (split bf16) -------
__global__ void norm_z_kernel(const float* __restrict__ z, float* __restrict__ znorm,
                              float* __restrict__ z2k, float* __restrict__ z2s,
                              short* __restrict__ Zs) {
    int t = blockIdx.x, c = threadIdx.x;
    int lane = c & 63, w = c >> 6;
    int b = t >> 10, hw = t & 1023;
    float x = z[((size_t)b * 256 + c) * 1024 + hw];
    float s = x * x;
#pragma unroll
    for (int m = 1; m < 64; m <<= 1) s += __shfl_xor(s, m, 64);
    __shared__ float ws4[4];
    if (lane == 0) ws4[w] = s;
    __syncthreads();
    float sk = ws4[0], sg = ws4[1] + ws4[2] + ws4[3];
    float nk = fmaxf(sqrtf(sk), 1e-12f), ng = fmaxf(sqrtf(sg), 1e-12f);
    float y = x / ((c < 64) ? nk : ng);
    znorm[(size_t)t * KD + c] = y;
    if (c == 0) {
        float zk2 = sk / (nk * nk), zg2 = sg / (ng * ng);
        z2k[t] = zk2; z2s[t] = zk2 + zg2;
    }
    short h = f2bf(y);      float hf = bf2f(h);
    short l = f2bf(y - hf);
    short* Zr = Zs + (size_t)t * K3;
    if (c < 64) { Zr[c] = h; Zr[64 + c] = h; Zr[128 + c] = l; }
    else { int cc = c - 64; Zr[192 + cc] = h; Zr[384 + cc] = h; Zr[576 + cc] = l; }
}

// ---------------- fused MFMA GEMM ----------------
// grid: x = token-block (32), y = code-block (128). Consecutive block ids share
// the same Es tile per XCD (id%8 round-robin) -> Es read ~once per XCD.
__global__ __launch_bounds__(256, 3)
void gemm_fused_kernel(const short* __restrict__ Zs, const short* __restrict__ Es,
                       const float* __restrict__ z2k, const float* __restrict__ e2k,
                       const float* __restrict__ z2s, const float* __restrict__ e2s,
                       u64* __restrict__ packed, float* __restrict__ scal,
                       float* __restrict__ part_m, float* __restrict__ part_z,
                       float* __restrict__ part_w,
                       float* __restrict__ candD, int* __restrict__ candN,
                       int* __restrict__ ncand) {
    __shared__ __align__(16) short As[128 * 64];   // [token_row][k] 64 bf16/row
    __shared__ __align__(16) short Bs[128 * 64];   // [code_row][k]
    const int tid = threadIdx.x;
    const int lane = tid & 63, wid = tid >> 6;
    const int wm = wid >> 1, wn = wid & 1;         // wave tile: 64(tok) x 64(code)
    const int t0 = blockIdx.x * 128, n0 = blockIdx.y * 128;

    f32x4 acc[4][4];
#pragma unroll
    for (int bi = 0; bi < 4; ++bi)
#pragma unroll
        for (int bj = 0; bj < 4; ++bj) {
            f32x4 zz = {0.f, 0.f, 0.f, 0.f};
            acc[bi][bj] = zz;
        }

    auto stage = [&](int k0) {
        const int rb0 = wid * 32;
#pragma unroll
        for (int c2 = 0; c2 < 4; ++c2) {
            int rb = rb0 + c2 * 8;
            int row = rb + (lane >> 3);
            int q = (lane & 7) ^ (lane >> 3);   // XOR-quad swizzle (rb%8==0)
            async_load16(Zs + (size_t)(t0 + row) * K3 + k0 + q * 8, &As[rb * 64]);
            async_load16(Es + (size_t)(n0 + row) * K3 + k0 + q * 8, &Bs[rb * 64]);
        }
    };
    auto compute_half = [&](int s) {
        bf16x8 bfv[4];
#pragma unroll
        for (int bj = 0; bj < 4; ++bj) {
            int brow = wn * 64 + bj * 16 + (lane & 15);
            int q = ((s << 2) | (lane >> 4)) ^ (brow & 7);
            bfv[bj] = *reinterpret_cast<const bf16x8*>(&Bs[brow * 64 + q * 8]);
        }
#pragma unroll
        for (int bi = 0; bi < 4; ++bi) {
            int arow = wm * 64 + bi * 16 + (lane & 15);
            int q = ((s << 2) | (lane >> 4)) ^ (arow & 7);
            bf16x8 af = *reinterpret_cast<const bf16x8*>(&As[arow * 64 + q * 8]);
#pragma unroll
            for (int bj = 0; bj < 4; ++bj)
                acc[bi][bj] = __builtin_amdgcn_mfma_f32_16x16x32_bf16(
                    af, bfv[bj], acc[bi][bj], 0, 0, 0);
        }
    };

    int k0 = 0;
    for (int r = 0; r < 3; ++r) {              // k-part: acc = -2*dot_k
        stage(k0); __syncthreads();
        compute_half(0); compute_half(1);
        __syncthreads(); k0 += 64;
    }

    // ---- mid-epilogue: dk = z2k + e2k + acc; stash bf16, accumulate sum(dk^2) ----
    float sdk2 = 0.f;
    unsigned dkp[4][4][2];
    {
        float e2kv[4];
#pragma unroll
        for (int bj = 0; bj < 4; ++bj)
            e2kv[bj] = e2k[n0 + wn * 64 + bj * 16 + (lane & 15)];
#pragma unroll
        for (int bi = 0; bi < 4; ++bi) {
            f32x4 z4 = *reinterpret_cast<const f32x4*>(
                &z2k[t0 + wm * 64 + bi * 16 + (lane >> 4) * 4]);
#pragma unroll
            for (int reg = 0; reg < 4; ++reg) {
#pragma unroll
                for (int bj = 0; bj < 4; ++bj) {
                    float dk = z4[reg] + e2kv[bj] + acc[bi][bj][reg];
                    sdk2 = fmaf(dk, dk, sdk2);
                    unsigned hb = (unsigned)(unsigned short)f2bf(dk);
                    if ((reg & 1) == 0) dkp[bi][bj][reg >> 1] = hb;
                    else                dkp[bi][bj][reg >> 1] |= hb << 16;
                }
            }
        }
    }

    for (int r = 0; r < 9; ++r) {              // g-part: acc += -2*dot_g
        stage(k0); __syncthreads();
        compute_half(0); compute_half(1);
        __syncthreads(); k0 += 64;
    }

    // ---- final epilogue ----
    char* lds = (char*)As;
    u64*   tokmin = (u64*)lds;                 // [128][2]   2048 B
    float* bmf    = (float*)(lds + 2048);      // [128]       512 B
    float* bthr   = (float*)(lds + 2560);      // [128]       512 B
    float* pzw    = (float*)(lds + 3072);      // [128][2][2] 2048 B

    float e2sv[4];
#pragma unroll
    for (int bj = 0; bj < 4; ++bj)
        e2sv[bj] = e2s[n0 + wn * 64 + bj * 16 + (lane & 15)];

    float sdg2 = 0.f;

    // pass 1: per-token wave-local packed min (d,n) + sum(dg^2) via dg = d - dk
#pragma unroll
    for (int bi = 0; bi < 4; ++bi) {
        u64 pmin[4] = {~0ull, ~0ull, ~0ull, ~0ull};
        f32x4 z4 = *reinterpret_cast<const f32x4*>(
            &z2s[t0 + wm * 64 + bi * 16 + (lane >> 4) * 4]);
#pragma unroll
        for (int reg = 0; reg < 4; ++reg) {
#pragma unroll
            for (int bj = 0; bj < 4; ++bj) {
                float d = z4[reg] + e2sv[bj] + acc[bi][bj][reg];
                float dkf = bf2f((short)(dkp[bi][bj][reg >> 1] >> ((reg & 1) * 16)));
                float dg = d - dkf;
                sdg2 = fmaf(dg, dg, sdg2);
                int n = n0 + wn * 64 + bj * 16 + (lane & 15);
                u64 pv = (((u64)__float_as_uint(d)) << 32) | (unsigned)n;
                if (pv < pmin[reg]) pmin[reg] = pv;
            }
        }
#pragma unroll
        for (int m = 1; m < 16; m <<= 1)
#pragma unroll
            for (int reg = 0; reg < 4; ++reg) {
                u64 o = __shfl_xor(pmin[reg], m, 64);
                if (o < pmin[reg]) pmin[reg] = o;
            }
        if ((lane & 15) == 0) {
#pragma unroll
            for (int reg = 0; reg < 4; ++reg) {
                int tl = wm * 64 + bi * 16 + (lane >> 4) * 4 + reg;
                tokmin[tl * 2 + wn] = pmin[reg];
            }
        }
    }
    __syncthreads();

    // owner step: block min -> global atomicMin (returns old => best-so-far)
    if (tid < 128) {
        int tl = tid;
        u64 bm = tokmin[tl * 2], b1 = tokmin[tl * 2 + 1];
        if (b1 < bm) bm = b1;
        u64 old = atomicMin(&packed[t0 + tl], bm);
        u64 gb = (old < bm) ? old : bm;
        float d_bmin = __uint_as_float((unsigned)(bm >> 32));
        bmf[tl] = -100.f * d_bmin;
        bthr[tl] = __uint_as_float((unsigned)(gb >> 32)) + DCUT;
    }
    __syncthreads();

    // pass 2: block-level softmax partials + candidate capture
#pragma unroll
    for (int bi = 0; bi < 4; ++bi) {
        float ez[4] = {0.f, 0.f, 0.f, 0.f}, ew[4] = {0.f, 0.f, 0.f, 0.f};
        f32x4 z4 = *reinterpret_cast<const f32x4*>(
            &z2s[t0 + wm * 64 + bi * 16 + (lane >> 4) * 4]);
#pragma unroll
        for (int reg = 0; reg < 4; ++reg) {
            int tl = wm * 64 + bi * 16 + (lane >> 4) * 4 + reg;
            int t = t0 + tl;
            float m_b = bmf[tl], thr = bthr[tl];
#pragma unroll
            for (int bj = 0; bj < 4; ++bj) {
                float d = z4[reg] + e2sv[bj] + acc[bi][bj][reg];
                float a = -100.f * d;
                float e = __expf(a - m_b);
                ez[reg] += e;
                ew[reg] = fmaf(a, e, ew[reg]);
                if (d <= thr) {
                    int pos = atomicAdd(&ncand[t], 1);
                    if (pos < CAP) {
                        candD[(size_t)t * CAP + pos] = d;
                        candN[(size_t)t * CAP + pos] = n0 + wn * 64 + bj * 16 + (lane & 15);
                    }
                }
            }
        }
#pragma unroll
        for (int m = 1; m < 16; m <<= 1)
#pragma unroll
            for (int reg = 0; reg < 4; ++reg) {
                ez[reg] += __shfl_xor(ez[reg], m, 64);
                ew[reg] += __shfl_xor(ew[reg], m, 64);
            }
        if ((lane & 15) == 0) {
#pragma unroll
            for (int reg = 0; reg < 4; ++reg) {
                int tl = wm * 64 + bi * 16 + (lane >> 4) * 4 + reg;
                pzw[(tl * 2 + wn) * 2 + 0] = ez[reg];
                pzw[(tl * 2 + wn) * 2 + 1] = ew[reg];
            }
        }
    }
    __syncthreads();

    // owner step 2: write per-block partials (coalesced)
    if (tid < 128) {
        int tl = tid;
        size_t o = (size_t)blockIdx.y * T_TOK + t0 + tl;
        part_m[o] = bmf[tl];
        part_z[o] = pzw[tl * 4 + 0] + pzw[tl * 4 + 2];
        part_w[o] = pzw[tl * 4 + 1] + pzw[tl * 4 + 3];
    }
    __syncthreads();

    // block-reduce d^2 partial sums
    float* red = (float*)As;
    red[tid] = sdk2; __syncthreads();
    for (int s = 128; s > 0; s >>= 1) { if (tid < s) red[tid] += red[tid + s]; __syncthreads(); }
    if (tid == 0) atomicAdd(&scal[0], red[0]);
    __syncthreads();
    red[tid] = sdg2; __syncthreads();
    for (int s = 128; s > 0; s >>= 1) { if (tid < s) red[tid] += red[tid + s]; __syncthreads(); }
    if (tid == 0) atomicAdd(&scal[1], red[0]);
}

// ---------------- combine: exact per-token softmax stats + idx unpack ----------------
__global__ void combine_kernel(const float* __restrict__ part_m, const float* __restrict__ part_z,
                               const float* __restrict__ part_w, const u64* __restrict__ packed,
                               float* __restrict__ m_arr, float* __restrict__ Z_arr,
                               int* __restrict__ idx_arr, float* __restrict__ out,
                               float* __restrict__ scal) {
    int lane = threadIdx.x;                 // 64
    int t = blockIdx.x * 64 + lane;
    float m = -3.0e38f, Z = 0.f, W = 0.f;
    for (int nb = 0; nb < NE / 128; ++nb) {
        size_t o = (size_t)nb * T_TOK + t;
        float mb = part_m[o], zb = part_z[o], wb = part_w[o];
        if (mb > m) { float s = __expf(m - mb); Z *= s; W *= s; m = mb; }
        float s2 = __expf(mb - m);
        Z = fmaf(zb, s2, Z); W = fmaf(wb, s2, W);
    }
    m_arr[t] = m; Z_arr[t] = Z;
    u64 pv = packed[t];
    int idx = (int)(pv & 0xFFFFFFFFull);
    idx_arr[t] = idx;
    out[1048581 + t] = (float)idx;
    float ent = m + logf(Z) - W / Z;        // -sum p log p for this token
#pragma unroll
    for (int mm = 1; mm < 64; mm <<= 1) ent += __shfl_xor(ent, mm, 64);
    if (lane == 0) atomicAdd(&scal[3], ent);
}

// ---------------- z_q gather + vq loss (LDS transpose, coalesced NCHW stores) --------
__global__ __launch_bounds__(256)
void zq_kernel(const float* __restrict__ enorm, const float* __restrict__ znorm,
               const int* __restrict__ idx_arr,
               float* __restrict__ out, float* __restrict__ scal) {
    __shared__ float q_lds[256][33];        // [c][token_local], padded
    __shared__ float red[256];
    int tid = threadIdx.x;
    int t0 = blockIdx.x * 32;               // 32 tokens per block, same b
    float sdq = 0.f;
    for (int tl = 0; tl < 32; ++tl) {
        int t = t0 + tl;
        float q = enorm[(size_t)idx_arr[t] * KD + tid];
        q_lds[tid][tl] = q;
        float zc = znorm[(size_t)t * KD + tid];
        float df = q - zc;
        sdq = fmaf(df, df, sdq);
    }
    __syncthreads();
    int b = t0 >> 10, hw0 = t0 & 1023;
    int cg = tid >> 5, hwl = tid & 31;
    for (int c0 = 0; c0 < 256; c0 += 8) {
        int c = c0 + cg;
        out[((size_t)(b * 256 + c)) * 1024 + hw0 + hwl] = q_lds[c][hwl];
    }
    red[tid] = sdq;
    __syncthreads();
    for (int s = 128; s > 0; s >>= 1) { if (tid < s) red[tid] += red[tid + s]; __syncthreads(); }
    if (tid == 0) atomicAdd(&scal[2], red[0]);
}

// ---------------- avg_probs scatter from candidates ----------------
__global__ void avg_scatter_kernel(const float* __restrict__ candD, const int* __restrict__ candN,
                                   const int* __restrict__ ncand, const float* __restrict__ m_arr,
                                   const float* __restrict__ Z_arr, float* __restrict__ avg_num) {
    int t = blockIdx.x, lane = threadIdx.x;  // 64
    int nc = min(ncand[t], CAP);
    float m = m_arr[t], Z = Z_arr[t];
    for (int i = lane; i < nc; i += 64) {
        float a = -100.f * candD[(size_t)t * CAP + i];
        atomicAdd(&avg_num[candN[(size_t)t * CAP + i]], __expf(a - m) / Z);
    }
}

// ---------------- final scalars ----------------
__global__ void finalize_kernel(const float* __restrict__ avg_num, const float* __restrict__ scal,
                                float* __restrict__ out) {
    __shared__ float red[256];
    int tid = threadIdx.x;
    float s = 0.f;
    for (int n = tid; n < NE; n += 256) {
        float avg = avg_num[n] * (1.f / 4096.f);
        s += avg * logf(avg + 1e-5f);
    }
    red[tid] = s;
    __syncthreads();
    for (int st = 128; st > 0; st >>= 1) { if (tid < st) red[tid] += red[tid + st]; __syncthreads(); }
    if (tid == 0) {
        float avg_ent = -red[0];
        float se = scal[3] * (1.f / 4096.f);
        float vq = scal[2] * (1.f / 1048576.f);
        out[1048576] = vq;
        out[1048577] = 0.25f * vq;
        out[1048578] = 0.1f * (se - avg_ent);
        out[1048579] = scal[0] * (1.f / 4096.f);
        out[1048580] = scal[1] * (1.f / 4096.f);
    }
}

// ---------------- host ----------------
extern "C" void kernel_launch(void* const* d_in, const int* in_sizes, int n_in,
                              void* d_out, int out_size, void* d_ws, size_t ws_size,
                              hipStream_t stream) {
    const float* z  = (const float*)d_in[0];
    const float* wk = (const float*)d_in[1];
    const float* wg = (const float*)d_in[2];
    float* out = (float*)d_out;

    char* ws = (char*)d_ws;
    size_t off = 0;
    auto alloc = [&](size_t bytes) {
        void* p = ws + off;
        off += (bytes + 255) & ~(size_t)255;
        return p;
    };
    float* enorm  = (float*)alloc((size_t)NE * KD * 4);        // 16.78 MB
    float* znorm  = (float*)alloc((size_t)T_TOK * KD * 4);     //  4.19 MB
    short* Es     = (short*)alloc((size_t)NE * K3 * 2);        // 25.17 MB
    short* Zs     = (short*)alloc((size_t)T_TOK * K3 * 2);     //  6.29 MB
    float* e2k    = (float*)alloc(NE * 4);
    float* e2s    = (float*)alloc(NE * 4);
    float* z2k    = (float*)alloc(T_TOK * 4);
    float* z2s    = (float*)alloc(T_TOK * 4);
    u64*   packed = (u64*)alloc(T_TOK * 8);
    float* m_arr  = (float*)alloc(T_TOK * 4);
    float* Z_arr  = (float*)alloc(T_TOK * 4);
    int*   idx_arr= (int*)alloc(T_TOK * 4);
    int*   ncand  = (int*)alloc(T_TOK * 4);
    float* part_m = (float*)alloc((size_t)(NE / 128) * T_TOK * 4);  // 2.10 MB
    float* part_z = (float*)alloc((size_t)(NE / 128) * T_TOK * 4);  // 2.10 MB
    float* part_w = (float*)alloc((size_t)(NE / 128) * T_TOK * 4);  // 2.10 MB
    float* candD  = (float*)alloc((size_t)T_TOK * CAP * 4);    // 12.58 MB
    int*   candN  = (int*)alloc((size_t)T_TOK * CAP * 4);      // 12.58 MB
    float* avg_num= (float*)alloc(NE * 4);
    float* scal   = (float*)alloc(8 * 4);                      // total ~84 MB

    vq_init_kernel<<<64, 256, 0, stream>>>(packed, avg_num, ncand, scal);
    norm_codes_kernel<<<NE, 256, 0, stream>>>(wk, wg, enorm, e2k, e2s, Es);
    norm_z_kernel<<<T_TOK, 256, 0, stream>>>(z, znorm, z2k, z2s, Zs);

    dim3 gg(T_TOK / 128, NE / 128);   // x = token-block, y = code-block
    gemm_fused_kernel<<<gg, 256, 0, stream>>>(Zs, Es, z2k, e2k, z2s, e2s,
                                              packed, scal, part_m, part_z, part_w,
                                              candD, candN, ncand);
    combine_kernel<<<T_TOK / 64, 64, 0, stream>>>(part_m, part_z, part_w, packed,
                                                  m_arr, Z_arr, idx_arr, out, scal);
    zq_kernel<<<T_TOK / 32, 256, 0, stream>>>(enorm, znorm, idx_arr, out, scal);
    avg_scatter_kernel<<<T_TOK, 64, 0, stream>>>(candD, candN, ncand, m_arr, Z_arr, avg_num);
    finalize_kernel<<<1, 256, 0, stream>>>(avg_num, scal, out);
}